// Round 1
// baseline (1121.663 us; speedup 1.0000x reference)
//
#include <hip/hip_runtime.h>
#include <cstddef>

#define NB 65536
#define SL 5

__device__ __forceinline__ float sigm(float x)   { return 1.0f / (1.0f + __expf(-x)); }
__device__ __forceinline__ float tanh_f(float x) { return 2.0f / (1.0f + __expf(-2.0f * x)) - 1.0f; }

// ---------------------------------------------------------------------------
// Phase A: 2x (message + attention-weighted sum + GRU), thread per (b,s).
// Writes x transposed as xt[s][feat(=d*4+k)][b] for coalesced access in B.
// s-major thread mapping => consecutive lanes have consecutive b => stores coalesced.
// ---------------------------------------------------------------------------
__global__ __launch_bounds__(256, 2) void msg_pass_kernel(
    const float* __restrict__ nf, const float* __restrict__ pos,
    const float* __restrict__ att,
    const float* __restrict__ msg_w, const float* __restrict__ msg_b,
    const float* __restrict__ gw_ih, const float* __restrict__ gw_hh,
    const float* __restrict__ gb_ih, const float* __restrict__ gb_hh,
    float* __restrict__ xt)
{
  const int t = blockIdx.x * 256 + threadIdx.x;   // t in [0, NB*SL)
  const int s = t / NB;
  const int b = t - s * NB;
  const size_t base = (size_t)b * SL + s;

  // load node features, positions, attention matrix (contiguous, float4)
  float tn[24], tp[24], ta[16];
  const float4* n4 = (const float4*)(nf  + base * 24);
  const float4* p4 = (const float4*)(pos + base * 24);
  const float4* a4 = (const float4*)(att + base * 16);
#pragma unroll
  for (int q = 0; q < 6; q++) {
    float4 v = n4[q];
    tn[q*4+0] = v.x; tn[q*4+1] = v.y; tn[q*4+2] = v.z; tn[q*4+3] = v.w;
  }
#pragma unroll
  for (int q = 0; q < 6; q++) {
    float4 v = p4[q];
    tp[q*4+0] = v.x; tp[q*4+1] = v.y; tp[q*4+2] = v.z; tp[q*4+3] = v.w;
  }
#pragma unroll
  for (int q = 0; q < 4; q++) {
    float4 v = a4[q];
    ta[q*4+0] = v.x; ta[q*4+1] = v.y; ta[q*4+2] = v.z; ta[q*4+3] = v.w;
  }

  // h init = concat(nodes_feature, pos) along feature dim
  float h[4][12];
#pragma unroll
  for (int k = 0; k < 4; k++) {
#pragma unroll
    for (int d = 0; d < 6; d++) { h[k][d] = tn[k*6+d]; h[k][6+d] = tp[k*6+d]; }
  }

#pragma unroll 1
  for (int pass = 0; pass < 2; ++pass) {
    // m_all = h @ msg_w.T + msg_b
    float ma[4][12];
#pragma unroll
    for (int k = 0; k < 4; k++) {
#pragma unroll
      for (int j = 0; j < 12; j++) {
        float acc = msg_b[j];
#pragma unroll
        for (int i = 0; i < 12; i++) acc = __builtin_fmaf(msg_w[j*12+i], h[k][i], acc);
        ma[k][j] = acc;
      }
    }
    // m_v[n][d] = sum_w att[n][w] * m_all[w][d]
    float mv[4][12];
#pragma unroll
    for (int n = 0; n < 4; n++) {
#pragma unroll
      for (int d = 0; d < 12; d++) {
        mv[n][d] = ta[n*4+0]*ma[0][d] + ta[n*4+1]*ma[1][d]
                 + ta[n*4+2]*ma[2][d] + ta[n*4+3]*ma[3][d];
      }
    }
    // GRU cell per node (torch gate order r, z, n)
#pragma unroll
    for (int n = 0; n < 4; n++) {
      float r[12], z[12], g[12];
#pragma unroll
      for (int j = 0; j < 12; j++) {
        float gi = gb_ih[j], gh = gb_hh[j];
#pragma unroll
        for (int i = 0; i < 12; i++) {
          gi = __builtin_fmaf(gw_ih[j*12+i], mv[n][i], gi);
          gh = __builtin_fmaf(gw_hh[j*12+i], h[n][i], gh);
        }
        r[j] = sigm(gi + gh);
      }
#pragma unroll
      for (int j = 0; j < 12; j++) {
        float gi = gb_ih[12+j], gh = gb_hh[12+j];
#pragma unroll
        for (int i = 0; i < 12; i++) {
          gi = __builtin_fmaf(gw_ih[(12+j)*12+i], mv[n][i], gi);
          gh = __builtin_fmaf(gw_hh[(12+j)*12+i], h[n][i], gh);
        }
        z[j] = sigm(gi + gh);
      }
#pragma unroll
      for (int j = 0; j < 12; j++) {
        float gi = gb_ih[24+j], gh = gb_hh[24+j];
#pragma unroll
        for (int i = 0; i < 12; i++) {
          gi = __builtin_fmaf(gw_ih[(24+j)*12+i], mv[n][i], gi);
          gh = __builtin_fmaf(gw_hh[(24+j)*12+i], h[n][i], gh);
        }
        g[j] = tanh_f(gi + r[j] * gh);
      }
#pragma unroll
      for (int j = 0; j < 12; j++) h[n][j] = (1.0f - z[j]) * g[j] + z[j] * h[n][j];
    }
  }

  // x[b,s,d*4+k] = h[k][d]; store transposed xt[(s*48 + d*4 + k)*NB + b]
#pragma unroll
  for (int d = 0; d < 12; d++) {
#pragma unroll
    for (int k = 0; k < 4; k++) {
      xt[(size_t)(s * 48 + d * 4 + k) * NB + b] = h[k][d];
    }
  }
}

// ---------------------------------------------------------------------------
// Phase B+C: bidirectional LSTM (5 steps) + MLP head.
// Thread = (batch, dir). dir = wave index (wave-uniform => weights are s_loads).
// c/h_next in scratch (runtime unit index, ~1% of instrs); h/x in registers.
// fw/bw final hidden exchanged via LDS; MLP + store on the fw wave.
// ---------------------------------------------------------------------------
__global__ __launch_bounds__(128, 2) void lstm_head_kernel(
    const float* __restrict__ xt,
    const float* __restrict__ wi_fw, const float* __restrict__ wh_fw,
    const float* __restrict__ bi_fw, const float* __restrict__ bh_fw,
    const float* __restrict__ wi_bw, const float* __restrict__ wh_bw,
    const float* __restrict__ bi_bw, const float* __restrict__ bh_bw,
    const float* __restrict__ e1w, const float* __restrict__ e1b,
    const float* __restrict__ e2w, const float* __restrict__ e2b,
    const float* __restrict__ e3w, const float* __restrict__ e3b,
    float* __restrict__ out)
{
  __shared__ float hfin[2][64][48];
  const int lane = threadIdx.x & 63;
  const int dir  = __builtin_amdgcn_readfirstlane(threadIdx.x >> 6);  // wave-uniform
  const int b    = blockIdx.x * 64 + lane;

  const float* __restrict__ wi = dir ? wi_bw : wi_fw;
  const float* __restrict__ wh = dir ? wh_bw : wh_fw;
  const float* __restrict__ bi = dir ? bi_bw : bi_fw;
  const float* __restrict__ bh = dir ? bh_bw : bh_fw;

  float hreg[48];               // registers (static indexing only)
#pragma unroll
  for (int k = 0; k < 48; k++) hreg[k] = 0.0f;
  float carr[48], hnarr[48];    // scratch (runtime indexing in unit loop)
  for (int k = 0; k < 48; k++) carr[k] = 0.0f;

#pragma unroll 1
  for (int st = 0; st < 5; ++st) {
    const int s = dir ? (4 - st) : st;
    float xv[48];
#pragma unroll
    for (int j = 0; j < 48; j++) xv[j] = xt[(size_t)(s * 48 + j) * NB + b];

#pragma unroll 1
    for (int j = 0; j < 48; j++) {   // unit loop (runtime) — gates i,f,g,o
      float gi = bi[j]       + bh[j];
      float gf = bi[48 + j]  + bh[48 + j];
      float gg = bi[96 + j]  + bh[96 + j];
      float go = bi[144 + j] + bh[144 + j];
      const float* __restrict__ wij = wi + j * 48;
      const float* __restrict__ whj = wh + j * 48;
#pragma unroll
      for (int k = 0; k < 48; k++) {
        const float xk = xv[k];
        const float hk = hreg[k];
        gi = __builtin_fmaf(wij[k],        xk, gi);
        gi = __builtin_fmaf(whj[k],        hk, gi);
        gf = __builtin_fmaf(wij[2304 + k], xk, gf);
        gf = __builtin_fmaf(whj[2304 + k], hk, gf);
        gg = __builtin_fmaf(wij[4608 + k], xk, gg);
        gg = __builtin_fmaf(whj[4608 + k], hk, gg);
        go = __builtin_fmaf(wij[6912 + k], xk, go);
        go = __builtin_fmaf(whj[6912 + k], hk, go);
      }
      const float c = sigm(gf) * carr[j] + sigm(gi) * tanh_f(gg);
      carr[j]  = c;
      hnarr[j] = sigm(go) * tanh_f(c);
    }
#pragma unroll
    for (int k = 0; k < 48; k++) hreg[k] = hnarr[k];
  }

  // exchange fw/bw final hidden states
#pragma unroll
  for (int k = 0; k < 48; k++) hfin[dir][lane][k] = hreg[k];
  __syncthreads();
  if (dir != 0) return;

  float hcat[96];
#pragma unroll
  for (int k = 0; k < 48; k++) { hcat[k] = hfin[0][lane][k]; hcat[48 + k] = hfin[1][lane][k]; }

  // MLP head: 96 -> 48 relu -> 36 relu -> 6
  float e1[48];
#pragma unroll
  for (int r = 0; r < 48; r++) {
    float a = e1b[r];
#pragma unroll
    for (int k = 0; k < 96; k++) a = __builtin_fmaf(e1w[r * 96 + k], hcat[k], a);
    e1[r] = a > 0.0f ? a : 0.0f;
  }
  float e2[36];
#pragma unroll
  for (int r = 0; r < 36; r++) {
    float a = e2b[r];
#pragma unroll
    for (int k = 0; k < 48; k++) a = __builtin_fmaf(e2w[r * 48 + k], e1[k], a);
    e2[r] = a > 0.0f ? a : 0.0f;
  }
#pragma unroll
  for (int r = 0; r < 6; r++) {
    float a = e3b[r];
#pragma unroll
    for (int k = 0; k < 36; k++) a = __builtin_fmaf(e3w[r * 36 + k], e2[k], a);
    out[(size_t)b * 6 + r] = a;
  }
}

extern "C" void kernel_launch(void* const* d_in, const int* in_sizes, int n_in,
                              void* d_out, int out_size, void* d_ws, size_t ws_size,
                              hipStream_t stream)
{
  const float* nf    = (const float*)d_in[0];
  const float* pos   = (const float*)d_in[1];
  const float* att   = (const float*)d_in[2];
  const float* msg_w = (const float*)d_in[3];
  const float* msg_b = (const float*)d_in[4];
  const float* gw_ih = (const float*)d_in[5];
  const float* gw_hh = (const float*)d_in[6];
  const float* gb_ih = (const float*)d_in[7];
  const float* gb_hh = (const float*)d_in[8];
  const float* wi_fw = (const float*)d_in[9];
  const float* wh_fw = (const float*)d_in[10];
  const float* bi_fw = (const float*)d_in[11];
  const float* bh_fw = (const float*)d_in[12];
  const float* wi_bw = (const float*)d_in[13];
  const float* wh_bw = (const float*)d_in[14];
  const float* bi_bw = (const float*)d_in[15];
  const float* bh_bw = (const float*)d_in[16];
  const float* e1w   = (const float*)d_in[17];
  const float* e1b   = (const float*)d_in[18];
  const float* e2w   = (const float*)d_in[19];
  const float* e2b   = (const float*)d_in[20];
  const float* e3w   = (const float*)d_in[21];
  const float* e3b   = (const float*)d_in[22];

  float* xt   = (float*)d_ws;   // [SL][48][NB] fp32 = 63 MB
  float* outp = (float*)d_out;

  msg_pass_kernel<<<(NB * SL) / 256, 256, 0, stream>>>(
      nf, pos, att, msg_w, msg_b, gw_ih, gw_hh, gb_ih, gb_hh, xt);

  lstm_head_kernel<<<NB / 64, 128, 0, stream>>>(
      xt, wi_fw, wh_fw, bi_fw, bh_fw, wi_bw, wh_bw, bi_bw, bh_bw,
      e1w, e1b, e2w, e2b, e3w, e3b, outp);
}